// Round 3
// baseline (363.295 us; speedup 1.0000x reference)
//
#include <hip/hip_runtime.h>

// CoarseMatching dual-softmax on MI355X — round 3.
// N=2, L=S=4800, C=256. sim = f0.f1^T/(256*0.1); conf = softmax_l * softmax_s.
// GEMM: bf16 hi/lo split -> K=768 bf16 MFMA GEMM, BK=64, XOR-swizzled LDS.
// Fused epilogue: e = exp(sim) (no max-sub: |sim/T| < ~4), stores e, LDS-reduced
// atomics accumulate rs = sum_s e, cs = sum_l e.
// conf pass (wave-per-row): conf = e^2 * rcp(rs) * rcp(cs), in place in d_out.

#define Ncst 2
#define Lc 4800
#define Sc 4800
#define Cc 256
#define K3 768          // 3*C expanded K
#define LP 4864         // 4800 padded to 38*128
#define THRC 0.2f

typedef float f32x4 __attribute__((ext_vector_type(4)));
typedef __bf16 bf16x8 __attribute__((ext_vector_type(8)));

#define AS1(p) ((__attribute__((address_space(1))) void*)(p))
#define AS3(p) ((__attribute__((address_space(3))) void*)(p))

__device__ inline unsigned short f2bf(float x) {
    unsigned u = __float_as_uint(x);
    unsigned r = (u + 0x7fffu + ((u >> 16) & 1u)) >> 16;
    return (unsigned short)r;
}
__device__ inline float bf2f(unsigned short h) {
    return __uint_as_float(((unsigned)h) << 16);
}

// ---------------- conversion (+ zero rs/cs): A3/B3 [N][LP][768] bf16 ---------
// A3 segments: [a_hi | a_hi | a_lo]; B3: [b_hi | b_lo | b_hi]
// => dot over 768 = hi.hi + hi.lo + lo.hi.
__global__ __launch_bounds__(256) void convert_kernel(
    const float* __restrict__ f0, const float* __restrict__ f1,
    unsigned short* __restrict__ A3, unsigned short* __restrict__ B3,
    float* __restrict__ rs, float* __restrict__ cs)
{
    int idx = blockIdx.x * 256 + threadIdx.x;      // over N*LP*(C/8)
    if (idx < Ncst * Lc) { rs[idx] = 0.f; cs[idx] = 0.f; }
    if (idx >= Ncst * LP * (Cc / 8)) return;
    int k8  = idx & (Cc / 8 - 1);                  // 0..31
    int row = (idx >> 5) % LP;
    int n   = idx / (LP * (Cc / 8));
    size_t base = ((size_t)n * LP + row) * K3 + k8 * 8;

    float av[8], bv[8];
    if (row < Lc) {
        const float4* pa = (const float4*)(f0 + ((size_t)n * Lc + row) * Cc + k8 * 8);
        float4 a0 = pa[0], a1 = pa[1];
        av[0]=a0.x; av[1]=a0.y; av[2]=a0.z; av[3]=a0.w;
        av[4]=a1.x; av[5]=a1.y; av[6]=a1.z; av[7]=a1.w;
        const float4* pb = (const float4*)(f1 + ((size_t)n * Sc + row) * Cc + k8 * 8);
        float4 b0 = pb[0], b1 = pb[1];
        bv[0]=b0.x; bv[1]=b0.y; bv[2]=b0.z; bv[3]=b0.w;
        bv[4]=b1.x; bv[5]=b1.y; bv[6]=b1.z; bv[7]=b1.w;
    } else {
        for (int i = 0; i < 8; ++i) { av[i] = 0.f; bv[i] = 0.f; }
    }

    unsigned short ahi[8], alo[8], bhi[8], blo[8];
#pragma unroll
    for (int i = 0; i < 8; ++i) {
        ahi[i] = f2bf(av[i]); alo[i] = f2bf(av[i] - bf2f(ahi[i]));
        bhi[i] = f2bf(bv[i]); blo[i] = f2bf(bv[i] - bf2f(bhi[i]));
    }
    *(uint4*)&A3[base]       = *(uint4*)ahi;
    *(uint4*)&A3[base + 256] = *(uint4*)ahi;
    *(uint4*)&A3[base + 512] = *(uint4*)alo;
    *(uint4*)&B3[base]       = *(uint4*)bhi;
    *(uint4*)&B3[base + 256] = *(uint4*)blo;
    *(uint4*)&B3[base + 512] = *(uint4*)bhi;
}

// ---------------- GEMM + fused exp + row/col sum accumulation ----------------
// 128x128 tile, BK=64, 4 waves (2x2), each wave 64x64 via 4x4 of 16x16x32 MFMA.
// LDS: row of 64 bf16 = 8 slots of 16B; physical slot = logical ^ (row&7).
// Fragment ds_read_b128 then spreads across all 32 banks (2-way = free).
__global__ __launch_bounds__(256) void gemm_kernel(
    const unsigned short* __restrict__ A3, const unsigned short* __restrict__ B3,
    float* __restrict__ eout, float* __restrict__ rs, float* __restrict__ cs)
{
    __shared__ unsigned short lA[128 * 64];   // 16 KB
    __shared__ unsigned short lB[128 * 64];   // 16 KB

    const int n    = blockIdx.z;
    const int tm   = blockIdx.y;
    const int tn   = blockIdx.x;
    const int tid  = threadIdx.x;
    const int wave = tid >> 6;
    const int lane = tid & 63;
    const int wm   = wave >> 1;     // 0..1
    const int wn   = wave & 1;      // 0..1
    const int ml   = lane & 15;
    const int kq   = lane >> 4;     // 0..3

    const unsigned short* Ab = A3 + ((size_t)n * LP + (size_t)tm * 128) * K3;
    const unsigned short* Bb = B3 + ((size_t)n * LP + (size_t)tn * 128) * K3;

    f32x4 acc[4][4] = {};

    for (int k0 = 0; k0 < K3; k0 += 64) {
        __syncthreads();
        // stage 16KB per matrix: 1024 slots of 16B; slot s: row=s>>3, q_log=(s&7)^(row&7)
#pragma unroll
        for (int cc = 0; cc < 4; ++cc) {
            int c    = wave * 4 + cc;            // 0..15
            int slot = c * 64 + lane;            // 0..1023
            int row  = slot >> 3;
            int ql   = (slot & 7) ^ (row & 7);
            const unsigned short* ga = Ab + (size_t)row * K3 + (k0 + ql * 8);
            const unsigned short* gb = Bb + (size_t)row * K3 + (k0 + ql * 8);
            __builtin_amdgcn_global_load_lds(AS1(ga), AS3(lA + (size_t)slot * 8), 16, 0, 0);
            __builtin_amdgcn_global_load_lds(AS1(gb), AS3(lB + (size_t)slot * 8), 16, 0, 0);
        }
        __syncthreads();

#pragma unroll
        for (int half = 0; half < 2; ++half) {
            bf16x8 af[4], bfr[4];
#pragma unroll
            for (int i = 0; i < 4; ++i) {
                int arow  = wm * 64 + i * 16 + ml;
                int aslot = arow * 8 + ((half * 4 + kq) ^ (arow & 7));
                af[i] = *(const bf16x8*)&lA[(size_t)aslot * 8];
                int brow  = wn * 64 + i * 16 + ml;
                int bslot = brow * 8 + ((half * 4 + kq) ^ (brow & 7));
                bfr[i] = *(const bf16x8*)&lB[(size_t)bslot * 8];
            }
#pragma unroll
            for (int i = 0; i < 4; ++i)
#pragma unroll
                for (int j = 0; j < 4; ++j)
                    acc[i][j] = __builtin_amdgcn_mfma_f32_16x16x32_bf16(af[i], bfr[j], acc[i][j], 0, 0, 0);
        }
    }
    __syncthreads();   // all LDS reads done before reuse as reduction buffer

    // ---- epilogue: e = exp(alpha*sim); store; LDS-reduce row/col sums ----
    // D[row][col]: col = lane&15, row = (lane>>4)*4 + r
    const float alpha = 5.0f / 128.0f;          // 1/(256*0.1), exact in fp32
#pragma unroll
    for (int i = 0; i < 4; ++i) {
#pragma unroll
        for (int r = 0; r < 4; ++r) {
            int gl = tm * 128 + wm * 64 + i * 16 + kq * 4 + r;
            bool rok = gl < Lc;
#pragma unroll
            for (int j = 0; j < 4; ++j) {
                int gs = tn * 128 + wn * 64 + j * 16 + ml;
                bool ok = rok && (gs < Sc);
                float ev = ok ? __expf(acc[i][j][r] * alpha) : 0.f;
                acc[i][j][r] = ev;
                if (ok) eout[((size_t)n * Lc + gl) * Sc + gs] = ev;
            }
        }
    }

    float* red = (float*)lA;   // red[0..255]=row partials [wn][128], [256..511]=col [wm][128]
    // row partials: sum over j, then over ml (xor 1,2,4,8 stays within quarter)
#pragma unroll
    for (int i = 0; i < 4; ++i) {
#pragma unroll
        for (int r = 0; r < 4; ++r) {
            float rp = acc[i][0][r] + acc[i][1][r] + acc[i][2][r] + acc[i][3][r];
            rp += __shfl_xor(rp, 1);
            rp += __shfl_xor(rp, 2);
            rp += __shfl_xor(rp, 4);
            rp += __shfl_xor(rp, 8);
            if (ml == 0) red[wn * 128 + wm * 64 + i * 16 + kq * 4 + r] = rp;
        }
    }
    // col partials: sum over i,r, then over kq (xor 16, 32)
#pragma unroll
    for (int j = 0; j < 4; ++j) {
        float cp = 0.f;
#pragma unroll
        for (int i = 0; i < 4; ++i)
#pragma unroll
            for (int r = 0; r < 4; ++r) cp += acc[i][j][r];
        cp += __shfl_xor(cp, 16);
        cp += __shfl_xor(cp, 32);
        if (kq == 0) red[256 + wm * 128 + wn * 64 + j * 16 + ml] = cp;
    }
    __syncthreads();
    if (tid < 128) {
        int gl = tm * 128 + tid;
        if (gl < Lc) atomicAdd(&rs[(size_t)n * Lc + gl], red[tid] + red[128 + tid]);
    } else {
        int t = tid - 128;
        int gs = tn * 128 + t;
        if (gs < Sc) atomicAdd(&cs[(size_t)n * Sc + gs], red[256 + t] + red[384 + t]);
    }
}

// ---------------- conf (wave-per-row): e -> conf = e^2*rcp(rs)*rcp(cs) -------
// 4 rows per 256-thread block; no barriers; shuffle row-max -> rcm.
__global__ __launch_bounds__(256) void conf_kernel(
    float* __restrict__ confio,
    const float* __restrict__ rs, const float* __restrict__ cs,
    float* __restrict__ rcm)
{
    const int wave = threadIdx.x >> 6;
    const int lane = threadIdx.x & 63;
    const int b = blockIdx.x * 4 + wave;          // n*Lc + l, 0..9599
    const int n = b / Lc;
    f32x4* row = (f32x4*)(confio + (size_t)b * Sc);
    const f32x4* csv = (const f32x4*)(cs + (size_t)n * Sc);
    const float riv = __builtin_amdgcn_rcpf(rs[b]);
    float lmax = 0.f;
    for (int g = lane; g < Sc / 4; g += 64) {     // 1200 granules
        f32x4 e4 = row[g];
        f32x4 c4 = csv[g];
        f32x4 o;
        o.x = e4.x * e4.x * riv * __builtin_amdgcn_rcpf(c4.x);
        o.y = e4.y * e4.y * riv * __builtin_amdgcn_rcpf(c4.y);
        o.z = e4.z * e4.z * riv * __builtin_amdgcn_rcpf(c4.z);
        o.w = e4.w * e4.w * riv * __builtin_amdgcn_rcpf(c4.w);
        __builtin_nontemporal_store(o, &row[g]);
        lmax = fmaxf(lmax, fmaxf(fmaxf(o.x, o.y), fmaxf(o.z, o.w)));
    }
    lmax = fmaxf(lmax, __shfl_xor(lmax, 1));
    lmax = fmaxf(lmax, __shfl_xor(lmax, 2));
    lmax = fmaxf(lmax, __shfl_xor(lmax, 4));
    lmax = fmaxf(lmax, __shfl_xor(lmax, 8));
    lmax = fmaxf(lmax, __shfl_xor(lmax, 16));
    lmax = fmaxf(lmax, __shfl_xor(lmax, 32));
    if (lane == 0) rcm[b] = lmax;
}

// ---------------- finalize: threshold + border + mutual-NN -------------------
// Gated by rowmax_conf > THR (any mask-true entry must equal rowmax > THR).
__global__ __launch_bounds__(256) void finalize_kernel(
    const float* __restrict__ conf, const float* __restrict__ rcm,
    const int* __restrict__ h0p, const int* __restrict__ w0p,
    const int* __restrict__ h1p, const int* __restrict__ w1p,
    float* __restrict__ out_match, float* __restrict__ out_j, float* __restrict__ out_mconf)
{
    int i = blockIdx.x * 256 + threadIdx.x;      // n*Lc + l
    if (i >= Ncst * Lc) return;
    int n = i / Lc, l = i % Lc;
    float mm = rcm[i];
    float fm = 0.f, fj = 0.f, fc = 0.f;
    if (mm > THRC) {
        int w0 = *w0p, w1 = *w1p;
        if ((l / w0) >= 2 && (l % w0) >= 2) {
            const float* rowp = conf + ((size_t)n * Lc + l) * Sc;
            for (int s = 0; s < Sc; ++s) {
                float c = rowp[s];
                if (c == mm && (s / w1) >= 2 && (s % w1) >= 2) {
                    bool ismax = true;
                    const float* colp = conf + (size_t)n * Lc * Sc + s;
                    for (int lp = 0; lp < Lc; ++lp) {
                        if (colp[(size_t)lp * Sc] > c) { ismax = false; break; }
                    }
                    if (ismax) { fm = 1.f; fj = (float)s; fc = c; break; }
                }
            }
        }
    }
    out_match[i] = fm; out_j[i] = fj; out_mconf[i] = fc;
}

extern "C" void kernel_launch(void* const* d_in, const int* in_sizes, int n_in,
                              void* d_out, int out_size, void* d_ws, size_t ws_size,
                              hipStream_t stream) {
    const float* f0 = (const float*)d_in[0];
    const float* f1 = (const float*)d_in[1];
    const int* h0p = (const int*)d_in[2];
    const int* w0p = (const int*)d_in[3];
    const int* h1p = (const int*)d_in[4];
    const int* w1p = (const int*)d_in[5];

    // workspace layout (bytes); total ~30 MB
    char* ws = (char*)d_ws;
    unsigned short* A3 = (unsigned short*)ws;                  // 14,942,208 B
    unsigned short* B3 = (unsigned short*)(ws + 14942208);     // 14,942,208 B
    float* rs  = (float*)(ws + 29884416);                      // 38,400 B each
    float* cs  = (float*)(ws + 29922816);
    float* rcm = (float*)(ws + 29961216);

    float* conf      = (float*)d_out;                          // [N][L][S]: e then conf
    float* out_match = conf + (size_t)Ncst * Lc * Sc;
    float* out_j     = out_match + Ncst * Lc;
    float* out_mconf = out_j + Ncst * Lc;

    convert_kernel<<<(Ncst * LP * (Cc / 8) + 255) / 256, 256, 0, stream>>>(f0, f1, A3, B3, rs, cs);

    dim3 gg(LP / 128, LP / 128, Ncst);   // 38 x 38 x 2
    gemm_kernel<<<gg, 256, 0, stream>>>(A3, B3, conf, rs, cs);

    conf_kernel<<<Ncst * Lc / 4, 256, 0, stream>>>(conf, rs, cs, rcm);

    finalize_kernel<<<(Ncst * Lc + 255) / 256, 256, 0, stream>>>(
        conf, rcm, h0p, w0p, h1p, w1p, out_match, out_j, out_mconf);
}